// Round 6
// baseline (3514.410 us; speedup 1.0000x reference)
//
#include <hip/hip_runtime.h>
#include <hip/hip_bf16.h>

// Sizes (fixed): T=512 tokens, D=256 embed, L=256 lstm, H=512 hidden. 4L=1024.

typedef _Float16 h2v __attribute__((ext_vector_type(2)));

#define BC(x) __builtin_bit_cast(h2v, (x))

__device__ __forceinline__ float fdot2f(h2v a, h2v b, float c) {
#if __has_builtin(__builtin_amdgcn_fdot2)
    return __builtin_amdgcn_fdot2(a, b, c, false);
#else
    return c + (float)a[0] * (float)b[0] + (float)a[1] * (float)b[1];
#endif
}

// ---------------------------------------------------------------------------
// prep4: convert all four U [256 x 1024] f32 -> packed half2 (k-pair, col).
// Uf[m][k2*1024 + col] = (U[2k2][col], U[2k2+1][col]) as 2xf16 in a uint.
// ---------------------------------------------------------------------------
__global__ __launch_bounds__(256) void prep4(const float* __restrict__ U0,
                                             const float* __restrict__ U1,
                                             const float* __restrict__ U2,
                                             const float* __restrict__ U3,
                                             unsigned int* __restrict__ Uf) {
    int which = blockIdx.x >> 9;
    const float* U = which == 0 ? U0 : which == 1 ? U1 : which == 2 ? U2 : U3;
    unsigned int* out = Uf + which * 131072;
    int idx = (blockIdx.x & 511) * 256 + threadIdx.x;  // < 131072
    int k2 = idx >> 10, col = idx & 1023;
    union { _Float16 h[2]; unsigned int u; } p;
    p.h[0] = (_Float16)U[(2 * k2) * 1024 + col];
    p.h[1] = (_Float16)U[(2 * k2 + 1) * 1024 + col];
    out[idx] = p.u;
}

// ---------------------------------------------------------------------------
// gemm_cat: fused fwd/bwd GEMM with virtual concat A.
// A(row) = [A0[rr*halfK ..], A1[(M-1-rr)*halfK ..]] where rr = rev? M-1-row: row.
// blockIdx.z selects (B, bias, C, rev = z && revZ1).
// ---------------------------------------------------------------------------
__global__ __launch_bounds__(256) void gemm_cat(
        const float* __restrict__ A0, const float* __restrict__ A1, int halfK,
        const float* __restrict__ Bz0, const float* __restrict__ Bz1,
        const float* __restrict__ bias0, const float* __restrict__ bias1,
        float* __restrict__ C0, float* __restrict__ C1,
        int M, int N, int K, int revZ1) {
    const float* B = blockIdx.z ? Bz1 : Bz0;
    const float* bias = blockIdx.z ? bias1 : bias0;
    float* C = blockIdx.z ? C1 : C0;
    int rev = blockIdx.z ? revZ1 : 0;

    __shared__ float sA[16][65];
    __shared__ float sB[16][65];
    int tid = threadIdx.x;
    int bm = blockIdx.y * 64, bn = blockIdx.x * 64;
    int tx = tid & 15, ty = tid >> 4;
    float acc[4][4] = {};
    for (int k0 = 0; k0 < K; k0 += 16) {
#pragma unroll
        for (int l = 0; l < 4; l++) {
            int flat = tid + 256 * l;        // 64 rows x 16 k
            int ml = flat >> 4, kk = flat & 15;
            int row = bm + ml;
            int rr = rev ? M - 1 - row : row;
            int kcol = k0 + kk;
            float val = (kcol < halfK) ? A0[rr * halfK + kcol]
                                       : A1[(M - 1 - rr) * halfK + kcol - halfK];
            sA[kk][ml] = val;
        }
#pragma unroll
        for (int l = 0; l < 4; l++) {
            int flat = tid + 256 * l;        // 16 k x 64 n
            int kk = flat >> 6, nl = flat & 63;
            sB[kk][nl] = B[(k0 + kk) * N + bn + nl];
        }
        __syncthreads();
#pragma unroll
        for (int kk = 0; kk < 16; kk++) {
            float a[4], b[4];
#pragma unroll
            for (int i = 0; i < 4; i++) a[i] = sA[kk][ty + 16 * i];
#pragma unroll
            for (int j = 0; j < 4; j++) b[j] = sB[kk][tx + 16 * j];
#pragma unroll
            for (int i = 0; i < 4; i++)
#pragma unroll
                for (int j = 0; j < 4; j++) acc[i][j] += a[i] * b[j];
        }
        __syncthreads();
    }
#pragma unroll
    for (int i = 0; i < 4; i++) {
        int r = bm + ty + 16 * i;
#pragma unroll
        for (int j = 0; j < 4; j++) {
            int cidx = bn + tx + 16 * j;
            float bv = bias ? bias[cidx] : 0.f;
            C[r * N + cidx] = acc[i][j] + bv;
        }
    }
}

// ---------------------------------------------------------------------------
// lstm_two: 2 blocks (fwd, bwd), 1024 threads, 1 block/CU (LDS-forced).
// Thread t owns gate column t. U (f16 packed, 512KB/dir) fully on-chip:
// k-pairs [0,36) in LDS (147KB), k-pairs [36,128) pinned in 92 AGPRs/thread
// via inline-asm v_accvgpr_write_b32.
//
// Rounds 1-5 lesson: the allocator ALWAYS targets max occupancy (8 waves/
// SIMD, 64 VGPR at 1024 thr) and spills plain VGPR values to scratch ->
// ~230KB/step/CU L2 reloads -> ~1240us, regardless of launch_bounds /
// waves_per_eu / SSA shape / "+v" asm pins. AGPR values from opaque inline
// asm CANNOT be rematerialized and AGPR spill is the costliest option;
// pressure 92a + ~34v <= 128 unified budget at 4 waves/SIMD. Reads back are
// volatile v_accvgpr_read_b32 so LICM can't hoist them (which would rebuild
// the 92-wide VGPR live set).
// ---------------------------------------------------------------------------
#define KLDS 36   // k-pairs in LDS
#define KREG 92   // k-pairs in AGPRs = 23 chunks of 4

#define CHUNKS(X) X(0) X(1) X(2) X(3) X(4) X(5) X(6) X(7) X(8) X(9) X(10) \
    X(11) X(12) X(13) X(14) X(15) X(16) X(17) X(18) X(19) X(20) X(21) X(22)

__global__ __attribute__((amdgpu_flat_work_group_size(1024, 1024),
                          amdgpu_waves_per_eu(4, 4)))
void lstm_two(
        const unsigned int* __restrict__ Ua, const unsigned int* __restrict__ Ub,
        const float* __restrict__ Pa, const float* __restrict__ Pb,
        float* __restrict__ Oa, float* __restrict__ Ob) {
    const unsigned int* U = blockIdx.x ? Ub : Ua;
    const float* P = blockIdx.x ? Pb : Pa;
    float* O = blockIdx.x ? Ob : Oa;

    __shared__ unsigned int sU[KLDS * 1024];        // 147456 B
    __shared__ __align__(16) _Float16 sH[256];      // 512 B
    __shared__ float sZ[1024];                      // 4096 B

    int t = threadIdx.x;  // 0..1023, owns gate column t

    // stage LDS-resident k-pairs of U
    for (int i = t; i < KLDS * 1024; i += 1024) sU[i] = U[i];

    // AGPR-resident k-pairs: 23 chunks x 4 words, pinned via inline asm
#define DECLA(i) unsigned ag##i##_0, ag##i##_1, ag##i##_2, ag##i##_3;
    CHUNKS(DECLA)
#undef DECLA
#define LOADA(i) { \
    unsigned w0 = U[(KLDS + 4 * i + 0) * 1024 + t]; \
    unsigned w1 = U[(KLDS + 4 * i + 1) * 1024 + t]; \
    unsigned w2 = U[(KLDS + 4 * i + 2) * 1024 + t]; \
    unsigned w3 = U[(KLDS + 4 * i + 3) * 1024 + t]; \
    asm volatile("v_accvgpr_write_b32 %0, %1" : "=a"(ag##i##_0) : "v"(w0)); \
    asm volatile("v_accvgpr_write_b32 %0, %1" : "=a"(ag##i##_1) : "v"(w1)); \
    asm volatile("v_accvgpr_write_b32 %0, %1" : "=a"(ag##i##_2) : "v"(w2)); \
    asm volatile("v_accvgpr_write_b32 %0, %1" : "=a"(ag##i##_3) : "v"(w3)); }
    CHUNKS(LOADA)
#undef LOADA

    float c = 0.f;
    if (t < 256) sH[t] = (_Float16)0.f;
    __syncthreads();

    const uint4* hp4 = (const uint4*)sH;  // 32 chunks x 4 h2v = 128 k-pairs
    float pc = P[t];
    for (int step = 0; step < 512; step++) {
        float pn = pc;
        if (step < 511) pn = P[(step + 1) * 1024 + t];
        float acc0 = pc, acc1 = 0.f;  // two interleaved dep-chains

        // k-pairs 0..35 from LDS (9 chunks): h via uniform b128 broadcast
#pragma unroll
        for (int ch = 0; ch < 9; ch++) {
            uint4 hc = hp4[ch];
            acc0 = fdot2f(BC(hc.x), BC(sU[(4 * ch + 0) * 1024 + t]), acc0);
            acc1 = fdot2f(BC(hc.y), BC(sU[(4 * ch + 1) * 1024 + t]), acc1);
            acc0 = fdot2f(BC(hc.z), BC(sU[(4 * ch + 2) * 1024 + t]), acc0);
            acc1 = fdot2f(BC(hc.w), BC(sU[(4 * ch + 3) * 1024 + t]), acc1);
        }
        // k-pairs 36..127 from AGPRs (23 chunks); volatile reads stay in-loop
#define DOTA(i) { uint4 hc = hp4[9 + i]; unsigned w0, w1, w2, w3; \
        asm volatile("v_accvgpr_read_b32 %0, %1" : "=v"(w0) : "a"(ag##i##_0)); \
        asm volatile("v_accvgpr_read_b32 %0, %1" : "=v"(w1) : "a"(ag##i##_1)); \
        asm volatile("v_accvgpr_read_b32 %0, %1" : "=v"(w2) : "a"(ag##i##_2)); \
        asm volatile("v_accvgpr_read_b32 %0, %1" : "=v"(w3) : "a"(ag##i##_3)); \
        acc0 = fdot2f(BC(hc.x), BC(w0), acc0); \
        acc1 = fdot2f(BC(hc.y), BC(w1), acc1); \
        acc0 = fdot2f(BC(hc.z), BC(w2), acc0); \
        acc1 = fdot2f(BC(hc.w), BC(w3), acc1); }
        CHUNKS(DOTA)
#undef DOTA

        float z = acc0 + acc1;
        // per-column activation (wave-uniform branch: 256-aligned ranges)
        float a;
        if ((t >> 8) == 2) a = 1.f - 2.f / (1.f + __expf(2.f * z));  // g: tanh
        else               a = 1.f / (1.f + __expf(-z));             // i,f,o
        sZ[t] = a;
        __syncthreads();
        if (t < 256) {
            float ig = sZ[t], fg = sZ[256 + t], gg = sZ[512 + t], og = sZ[768 + t];
            c = fg * c + ig * gg;
            float h = og * (1.f - 2.f / (1.f + __expf(2.f * c)));
            O[step * 256 + t] = h;
            sH[t] = (_Float16)h;
        }
        __syncthreads();
        pc = pn;
    }
}

// ---------------------------------------------------------------------------
// head: S[i][j] = sum_h tanh(HF[i][h] + MF[j][h]) * w[h] + outBias
// ---------------------------------------------------------------------------
__global__ __launch_bounds__(256) void head_kernel(const float* __restrict__ HF,
                                                   const float* __restrict__ MF,
                                                   const float* __restrict__ w,
                                                   const float* __restrict__ outb,
                                                   float* __restrict__ S) {
    int i = blockIdx.x;
    __shared__ float sHF[512], sW[512];
    int tid = threadIdx.x;
    sHF[tid] = HF[i * 512 + tid];
    sHF[tid + 256] = HF[i * 512 + 256 + tid];
    sW[tid] = w[tid];
    sW[tid + 256] = w[tid + 256];
    __syncthreads();
    int lane = tid & 63, wv = tid >> 6;
    float ob = outb[0];
    for (int j = wv; j < 512; j += 4) {
        const float* mf = MF + j * 512;
        float acc = 0.f;
#pragma unroll
        for (int r = 0; r < 8; r++) {
            int h = lane + 64 * r;
            float x = sHF[h] + mf[h];
            acc += sW[h] * (1.f - 2.f / (1.f + __expf(2.f * x)));
        }
#pragma unroll
        for (int off = 32; off; off >>= 1) acc += __shfl_down(acc, off);
        if (lane == 0) S[i * 512 + j] = acc + ob;
    }
}

// ---------------------------------------------------------------------------
extern "C" void kernel_launch(void* const* d_in, const int* in_sizes, int n_in,
                              void* d_out, int out_size, void* d_ws, size_t ws_size,
                              hipStream_t stream) {
    const float* emb      = (const float*)d_in[0];
    const float* W_f1     = (const float*)d_in[1];
    const float* U_f1     = (const float*)d_in[2];
    const float* b_f1     = (const float*)d_in[3];
    const float* W_b1     = (const float*)d_in[4];
    const float* U_b1     = (const float*)d_in[5];
    const float* b_b1     = (const float*)d_in[6];
    const float* W_f2     = (const float*)d_in[7];
    const float* U_f2     = (const float*)d_in[8];
    const float* b_f2     = (const float*)d_in[9];
    const float* W_b2     = (const float*)d_in[10];
    const float* U_b2     = (const float*)d_in[11];
    const float* b_b2     = (const float*)d_in[12];
    const float* FOH      = (const float*)d_in[13];
    const float* FOM      = (const float*)d_in[14];
    const float* hidBias  = (const float*)d_in[15];
    const float* outLayer = (const float*)d_in[16];
    const float* outBias  = (const float*)d_in[17];
    float* out = (float*)d_out;

    // workspace carve (16 MB total)
    unsigned int* uf = (unsigned int*)d_ws;          // 4 x 131072 uints = 2MB
    unsigned int* uf_f1 = uf;
    unsigned int* uf_b1 = uf + 131072;
    unsigned int* uf_f2 = uf + 262144;
    unsigned int* uf_b2 = uf + 393216;
    float* f = (float*)d_ws + 524288;
    float* P1f = f;                 // 512x1024
    float* P1b = f + 524288;
    float* P2f = f + 1048576;
    float* P2b = f + 1572864;
    float* rf1 = f + 2097152;       // 512x256
    float* rb1 = f + 2228224;
    float* rf2 = f + 2359296;
    float* rb2 = f + 2490368;
    float* HFb  = f + 2621440;      // 512x512 (includes hidBias)
    float* MFb  = f + 2883584;

    prep4<<<2048, 256, 0, stream>>>(U_f1, U_b1, U_f2, U_b2, uf);

    // layer 1: A = emb (K == halfK, A1 half unused), z=1 reversed
    gemm_cat<<<dim3(16, 8, 2), 256, 0, stream>>>(
        emb, emb, 256, W_f1, W_b1, b_f1, b_b1, P1f, P1b, 512, 1024, 256, 1);

    lstm_two<<<2, 1024, 0, stream>>>(uf_f1, uf_b1, P1f, P1b, rf1, rb1);

    // layer 2: A = concat(rf1, rev rb1), z=1 reversed
    gemm_cat<<<dim3(16, 8, 2), 256, 0, stream>>>(
        rf1, rb1, 256, W_f2, W_b2, b_f2, b_b2, P2f, P2b, 512, 1024, 512, 1);

    lstm_two<<<2, 1024, 0, stream>>>(uf_f2, uf_b2, P2f, P2b, rf2, rb2);

    // head projections: A = concat(rf2, rev rb2), both z unreversed
    gemm_cat<<<dim3(8, 8, 2), 256, 0, stream>>>(
        rf2, rb2, 256, FOH, FOM, hidBias, nullptr, HFb, MFb, 512, 512, 512, 0);

    head_kernel<<<512, 256, 0, stream>>>(HFb, MFb, outLayer, outBias, out);
}

// Round 7
// 2777.691 us; speedup vs baseline: 1.2652x; 1.2652x over previous
//
#include <hip/hip_runtime.h>
#include <hip/hip_bf16.h>

// Sizes (fixed): T=512 tokens, D=256 embed, L=256 lstm, H=512 hidden. 4L=1024.

typedef _Float16 h2v __attribute__((ext_vector_type(2)));

#define BC(x) __builtin_bit_cast(h2v, (x))

__device__ __forceinline__ float fdot2f(h2v a, h2v b, float c) {
#if __has_builtin(__builtin_amdgcn_fdot2)
    return __builtin_amdgcn_fdot2(a, b, c, false);
#else
    return c + (float)a[0] * (float)b[0] + (float)a[1] * (float)b[1];
#endif
}

// ---------------------------------------------------------------------------
// prep4: convert all four U [256 x 1024] f32 -> packed half2 (k-pair, col).
// Uf[m][k2*1024 + col] = (U[2k2][col], U[2k2+1][col]) as 2xf16 in a uint.
// ---------------------------------------------------------------------------
__global__ __launch_bounds__(256) void prep4(const float* __restrict__ U0,
                                             const float* __restrict__ U1,
                                             const float* __restrict__ U2,
                                             const float* __restrict__ U3,
                                             unsigned int* __restrict__ Uf) {
    int which = blockIdx.x >> 9;
    const float* U = which == 0 ? U0 : which == 1 ? U1 : which == 2 ? U2 : U3;
    unsigned int* out = Uf + which * 131072;
    int idx = (blockIdx.x & 511) * 256 + threadIdx.x;  // < 131072
    int k2 = idx >> 10, col = idx & 1023;
    union { _Float16 h[2]; unsigned int u; } p;
    p.h[0] = (_Float16)U[(2 * k2) * 1024 + col];
    p.h[1] = (_Float16)U[(2 * k2 + 1) * 1024 + col];
    out[idx] = p.u;
}

// ---------------------------------------------------------------------------
// gemm_cat: fused fwd/bwd GEMM with virtual concat A.
// A(row) = [A0[rr*halfK ..], A1[(M-1-rr)*halfK ..]], rr = rev? M-1-row : row.
// blockIdx.z selects (B, bias, C, rev = z && revZ1).
// ---------------------------------------------------------------------------
__global__ __launch_bounds__(256) void gemm_cat(
        const float* __restrict__ A0, const float* __restrict__ A1, int halfK,
        const float* __restrict__ Bz0, const float* __restrict__ Bz1,
        const float* __restrict__ bias0, const float* __restrict__ bias1,
        float* __restrict__ C0, float* __restrict__ C1,
        int M, int N, int K, int revZ1) {
    const float* B = blockIdx.z ? Bz1 : Bz0;
    const float* bias = blockIdx.z ? bias1 : bias0;
    float* C = blockIdx.z ? C1 : C0;
    int rev = blockIdx.z ? revZ1 : 0;

    __shared__ float sA[16][65];
    __shared__ float sB[16][65];
    int tid = threadIdx.x;
    int bm = blockIdx.y * 64, bn = blockIdx.x * 64;
    int tx = tid & 15, ty = tid >> 4;
    float acc[4][4] = {};
    for (int k0 = 0; k0 < K; k0 += 16) {
#pragma unroll
        for (int l = 0; l < 4; l++) {
            int flat = tid + 256 * l;        // 64 rows x 16 k
            int ml = flat >> 4, kk = flat & 15;
            int row = bm + ml;
            int rr = rev ? M - 1 - row : row;
            int kcol = k0 + kk;
            float val = (kcol < halfK) ? A0[rr * halfK + kcol]
                                       : A1[(M - 1 - rr) * halfK + kcol - halfK];
            sA[kk][ml] = val;
        }
#pragma unroll
        for (int l = 0; l < 4; l++) {
            int flat = tid + 256 * l;        // 16 k x 64 n
            int kk = flat >> 6, nl = flat & 63;
            sB[kk][nl] = B[(k0 + kk) * N + bn + nl];
        }
        __syncthreads();
#pragma unroll
        for (int kk = 0; kk < 16; kk++) {
            float a[4], b[4];
#pragma unroll
            for (int i = 0; i < 4; i++) a[i] = sA[kk][ty + 16 * i];
#pragma unroll
            for (int j = 0; j < 4; j++) b[j] = sB[kk][tx + 16 * j];
#pragma unroll
            for (int i = 0; i < 4; i++)
#pragma unroll
                for (int j = 0; j < 4; j++) acc[i][j] += a[i] * b[j];
        }
        __syncthreads();
    }
#pragma unroll
    for (int i = 0; i < 4; i++) {
        int r = bm + ty + 16 * i;
#pragma unroll
        for (int j = 0; j < 4; j++) {
            int cidx = bn + tx + 16 * j;
            float bv = bias ? bias[cidx] : 0.f;
            C[r * N + cidx] = acc[i][j] + bv;
        }
    }
}

// ---------------------------------------------------------------------------
// lstm_sync: 8 blocks = 2 directions x 4 groups, 512 threads each.
// Group g of a direction owns hidden units [g*64, (g+1)*64) -> 256 gate
// columns (gate-major local index lc = G*64+u, global col = G*256+g*64+u).
// Per-thread register U = 64 words (16 uint4): pressure ~84 < the 128-VGPR
// cap the backend picks for 512-thr blocks (observed rounds 1-3). U is 100%
// register-resident across 8 CUs; no LDS-U, no spill-by-construction.
//
// Rounds 1-6 lesson: allocator VGPR target is a function of block size only
// (512->128, 1024->64); attributes/SSA/inline-asm cannot raise it. Fit under
// the cap by splitting across CUs, sync via L2.
//
// Per step: dot-partials -> LDS reduce -> gates -> owning 64 units update
// c,h locally -> write 64-float h slice to Hb[par] -> release atomicAdd on
// cnt[dir][step] -> spin acquire until all 4 groups arrive -> reload full h
// (L1-bypassing atomic loads) -> repack f16 into sHp. Parity double-buffer
// makes write(s+2) vs read(s) safe; per-step counters (memset before launch)
// make the barrier single-use. 8 small blocks are trivially co-resident.
// ---------------------------------------------------------------------------
__global__ __launch_bounds__(512, 2) void lstm_sync(
        const unsigned int* __restrict__ Uf,   // [2][131072]
        const float* __restrict__ P,           // [2][512*1024]
        float* __restrict__ Out,               // [2][512*256]
        float* __restrict__ Hb,                // [2 parity][2 dir][256]
        int* __restrict__ cnt) {               // [2 dir][512], zeroed
    int dir = blockIdx.x >> 2;
    int g   = blockIdx.x & 3;
    const unsigned int* U = Uf + dir * 131072;
    const float* Pd = P + dir * (512 * 1024);
    float* Od = Out + dir * (512 * 256);
    int* cn = cnt + dir * 512;

    int t = threadIdx.x;
    int lc = t & 255;            // local column, gate-major
    int hh = t >> 8;             // k-half (wave-uniform)
    int G = lc >> 6, u = lc & 63;
    int gc = G * 256 + g * 64 + u;   // global gate column

    __shared__ unsigned sHp[128];    // h as 128 packed f16-pairs
    __shared__ float sPart[512];
    __shared__ float sG[256];

    // one-time: 64 k-pairs of U into registers (16 uint4, fully unrolled)
    uint4 uq[16];
#pragma unroll
    for (int i = 0; i < 16; i++) {
        int kp = hh * 64 + 4 * i;
        uq[i].x = U[(kp + 0) * 1024 + gc];
        uq[i].y = U[(kp + 1) * 1024 + gc];
        uq[i].z = U[(kp + 2) * 1024 + gc];
        uq[i].w = U[(kp + 3) * 1024 + gc];
    }

    if (t < 128) sHp[t] = 0u;
    float cst = 0.f;
    __syncthreads();

    float pc = (t < 256) ? Pd[gc] : 0.f;
    for (int s = 0; s < 512; s++) {
        float pn = (s < 511 && t < 256) ? Pd[(s + 1) * 1024 + gc] : 0.f;

        float a0 = 0.f, a1 = 0.f;
#pragma unroll
        for (int i = 0; i < 16; i++) {
            uint4 hc = ((const uint4*)sHp)[hh * 16 + i];  // wave-uniform bcast
            a0 = fdot2f(BC(hc.x), BC(uq[i].x), a0);
            a1 = fdot2f(BC(hc.y), BC(uq[i].y), a1);
            a0 = fdot2f(BC(hc.z), BC(uq[i].z), a0);
            a1 = fdot2f(BC(hc.w), BC(uq[i].w), a1);
        }
        sPart[t] = a0 + a1;
        __syncthreads();
        if (t < 256) {
            float z = pc + sPart[t] + sPart[t + 256];
            sG[t] = (G == 2) ? 1.f - 2.f / (1.f + __expf(2.f * z))   // tanh
                             : 1.f / (1.f + __expf(-z));             // sigmoid
        }
        __syncthreads();
        int par = s & 1;
        if (t < 64) {   // wave 0 updates this group's 64 units
            float ig = sG[t], fg = sG[64 + t], gg = sG[128 + t], og = sG[192 + t];
            cst = fg * cst + ig * gg;
            float h = og * (1.f - 2.f / (1.f + __expf(2.f * cst)));
            Od[s * 256 + g * 64 + t] = h;
            Hb[(par * 2 + dir) * 256 + g * 64 + t] = h;
        }
        if (t == 0) {   // same wave as the h writes -> vmcnt covers them
            __threadfence();
            __hip_atomic_fetch_add(&cn[s], 1, __ATOMIC_RELEASE,
                                   __HIP_MEMORY_SCOPE_AGENT);
            while (__hip_atomic_load(&cn[s], __ATOMIC_ACQUIRE,
                                     __HIP_MEMORY_SCOPE_AGENT) < 4)
                __builtin_amdgcn_s_sleep(1);
        }
        __syncthreads();
        if (t < 128) {  // reload full h, bypass L1 (atomic b64), pack f16
            unsigned long long w = __hip_atomic_load(
                (const unsigned long long*)&Hb[(par * 2 + dir) * 256 + 2 * t],
                __ATOMIC_RELAXED, __HIP_MEMORY_SCOPE_AGENT);
            float2 hf = __builtin_bit_cast(float2, w);
            union { _Float16 h[2]; unsigned u_; } pk;
            pk.h[0] = (_Float16)hf.x;
            pk.h[1] = (_Float16)hf.y;
            sHp[t] = pk.u_;
        }
        __syncthreads();
        pc = pn;
    }
}

// ---------------------------------------------------------------------------
// head: S[i][j] = sum_h tanh(HF[i][h] + MF[j][h]) * w[h] + outBias
// ---------------------------------------------------------------------------
__global__ __launch_bounds__(256) void head_kernel(const float* __restrict__ HF,
                                                   const float* __restrict__ MF,
                                                   const float* __restrict__ w,
                                                   const float* __restrict__ outb,
                                                   float* __restrict__ S) {
    int i = blockIdx.x;
    __shared__ float sHF[512], sW[512];
    int tid = threadIdx.x;
    sHF[tid] = HF[i * 512 + tid];
    sHF[tid + 256] = HF[i * 512 + 256 + tid];
    sW[tid] = w[tid];
    sW[tid + 256] = w[tid + 256];
    __syncthreads();
    int lane = tid & 63, wv = tid >> 6;
    float ob = outb[0];
    for (int j = wv; j < 512; j += 4) {
        const float* mf = MF + j * 512;
        float acc = 0.f;
#pragma unroll
        for (int r = 0; r < 8; r++) {
            int h = lane + 64 * r;
            float x = sHF[h] + mf[h];
            acc += sW[h] * (1.f - 2.f / (1.f + __expf(2.f * x)));
        }
#pragma unroll
        for (int off = 32; off; off >>= 1) acc += __shfl_down(acc, off);
        if (lane == 0) S[i * 512 + j] = acc + ob;
    }
}

// ---------------------------------------------------------------------------
extern "C" void kernel_launch(void* const* d_in, const int* in_sizes, int n_in,
                              void* d_out, int out_size, void* d_ws, size_t ws_size,
                              hipStream_t stream) {
    const float* emb      = (const float*)d_in[0];
    const float* W_f1     = (const float*)d_in[1];
    const float* U_f1     = (const float*)d_in[2];
    const float* b_f1     = (const float*)d_in[3];
    const float* W_b1     = (const float*)d_in[4];
    const float* U_b1     = (const float*)d_in[5];
    const float* b_b1     = (const float*)d_in[6];
    const float* W_f2     = (const float*)d_in[7];
    const float* U_f2     = (const float*)d_in[8];
    const float* b_f2     = (const float*)d_in[9];
    const float* W_b2     = (const float*)d_in[10];
    const float* U_b2     = (const float*)d_in[11];
    const float* b_b2     = (const float*)d_in[12];
    const float* FOH      = (const float*)d_in[13];
    const float* FOM      = (const float*)d_in[14];
    const float* hidBias  = (const float*)d_in[15];
    const float* outLayer = (const float*)d_in[16];
    const float* outBias  = (const float*)d_in[17];
    float* out = (float*)d_out;

    // workspace carve (16 MB total)
    unsigned int* uf = (unsigned int*)d_ws;          // 4 x 131072 uints = 2MB
    float* f = (float*)d_ws + 524288;
    float* P1   = f;                 // [2][512*1024]  (P1f, P1b contiguous)
    float* P2   = f + 1048576;       // [2][512*1024]
    float* R1   = f + 2097152;       // [2][512*256]   (rf1, rb1 contiguous)
    float* R2   = f + 2359296;       // [2][512*256]
    float* HFb  = f + 2621440;       // 512x512 (includes hidBias)
    float* MFb  = f + 2883584;       // 512x512
    float* Hb   = f + 3145728;       // [2 parity][2 dir][256] = 1024 floats
    int*   cnt  = (int*)(f + 3146752);  // [2][512] = 4KB

    prep4<<<2048, 256, 0, stream>>>(U_f1, U_b1, U_f2, U_b2, uf);

    // layer 1: A = emb (K == halfK, A1 half unused), z=1 reversed
    gemm_cat<<<dim3(16, 8, 2), 256, 0, stream>>>(
        emb, emb, 256, W_f1, W_b1, b_f1, b_b1, P1, P1 + 524288,
        512, 1024, 256, 1);

    hipMemsetAsync(cnt, 0, 2 * 512 * sizeof(int), stream);
    lstm_sync<<<8, 512, 0, stream>>>(uf, P1, R1, Hb, cnt);

    // layer 2: A = concat(rf1, rev rb1), z=1 reversed
    gemm_cat<<<dim3(16, 8, 2), 256, 0, stream>>>(
        R1, R1 + 131072, 256, W_f2, W_b2, b_f2, b_b2, P2, P2 + 524288,
        512, 1024, 512, 1);

    hipMemsetAsync(cnt, 0, 2 * 512 * sizeof(int), stream);
    lstm_sync<<<8, 512, 0, stream>>>(uf + 262144, P2, R2, Hb, cnt);

    // head projections: A = concat(rf2, rev rb2), both z unreversed
    gemm_cat<<<dim3(8, 8, 2), 256, 0, stream>>>(
        R2, R2 + 131072, 256, FOH, FOM, hidBias, nullptr, HFb, MFb,
        512, 512, 512, 0);

    head_kernel<<<512, 256, 0, stream>>>(HFb, MFb, outLayer, outBias, out);
}